// Round 6
// baseline (976.649 us; speedup 1.0000x reference)
//
#include <hip/hip_runtime.h>
#include <math.h>

#define N_NODES 20000
#define N_EDGESI 200000
#define E_TOT   220000
#define N_FEAT  2048
#define H1      512
#define H2      30

typedef __bf16 bf16x8 __attribute__((ext_vector_type(8)));
typedef float  floatx4 __attribute__((ext_vector_type(4)));

// LDS-only barrier (no vmcnt drain): prefetch loads stay in flight across it.
__device__ __forceinline__ void lds_barrier() {
    asm volatile("s_waitcnt lgkmcnt(0)" ::: "memory");
    __builtin_amdgcn_s_barrier();
}

__device__ __forceinline__ unsigned short f2bf(float f) {   // RNE
    unsigned int u = __float_as_uint(f);
    unsigned int r = (u + 0x7FFF + ((u >> 16) & 1)) >> 16;
    return (unsigned short)r;
}
__device__ __forceinline__ unsigned int packtrunc(float a, float b) {
    return (__float_as_uint(a) >> 16) | (__float_as_uint(b) & 0xFFFF0000u);
}
__device__ __forceinline__ unsigned int packrne(float a, float b) {
    return (unsigned int)f2bf(a) | ((unsigned int)f2bf(b) << 16);
}
__device__ __forceinline__ bf16x8 u4_to_bf(uint4 u) {
    union { uint4 u; bf16x8 b; } cv; cv.u = u; return cv.b;
}

// ---- W1 conversion: w1bf[k][n] (straight) + w1tbf[n][k] (transposed) -------
__global__ __launch_bounds__(256) void cvtW1(const float* __restrict__ W1,
                                             unsigned short* __restrict__ w1bf,
                                             unsigned short* __restrict__ w1tbf) {
    __shared__ float tile[32][33];
    const int bk = blockIdx.y * 32, bn = blockIdx.x * 32;
    const int tc = threadIdx.x & 31, tr = threadIdx.x >> 5;  // 8 rows/pass
    for (int r = tr; r < 32; r += 8) {
        float v = W1[(size_t)(bk + r) * H1 + bn + tc];
        w1bf[(size_t)(bk + r) * H1 + bn + tc] = f2bf(v);
        tile[r][tc] = v;
    }
    __syncthreads();
    for (int r = tr; r < 32; r += 8) {
        w1tbf[(size_t)(bn + r) * N_FEAT + bk + tc] = f2bf(tile[tc][r]);
    }
}

// ---- GEMM1: xw1 = features @ W1 --------------------------------------------
// A (HBM-heavy, fp32) staged in LDS (dbuf, reg-prefetch+pack, R3 structure).
// B (2MB, L2-resident) loaded FRAGMENT-DIRECT from global into registers,
// prefetched 1 iter ahead, ping-ponged b0/b1 across an unroll-2 loop (no
// runtime-indexed reg arrays). Removes 2/3 of the LDS traffic from the
// barrier chain (36 -> 12 LDS instrs/block-iter). 64x128 tile, 1252 blocks.
__global__ __launch_bounds__(256, 5) void gemm1_mfma(const float* __restrict__ A,          // [20000,2048] fp32
                                                     const unsigned short* __restrict__ Bt, // [512,2048] bf16
                                                     unsigned short* __restrict__ C,        // [20000,512] bf16
                                                     const float* __restrict__ atts,
                                                     const float* __restrict__ attd,
                                                     float* __restrict__ a1s,
                                                     float* __restrict__ a1d) {
    __shared__ unsigned short As[2][64 * 40];
    const int blk = blockIdx.x;
    const int xcd = blk & 7, rr = blk >> 3;
    const int ntile = rr & 3, group = rr >> 2;
    const int stripe = group * 8 + xcd;
    if (stripe >= 313) return;
    const int bm = stripe * 64, bn = ntile * 128;
    const int t = threadIdx.x;
    const int lane = t & 63, w = t >> 6;
    const int wm = w >> 1, wn = w & 1;          // wave: rows wm*32..+31, cols wn*64..+63
    const int ln = lane & 15, qd = lane >> 4;
    const int r0 = t >> 2, cs = (t & 3) * 8;    // A staging slice (row r0, 8 floats at cs)

    int gra = bm + r0; if (gra > N_NODES - 1) gra = N_NODES - 1;
    const float* apA = A + (size_t)gra * N_FEAT + cs;

    // per-lane B fragment pointers (16B contiguous in Bt per fragment)
    const unsigned short* bfp[4];
#pragma unroll
    for (int j = 0; j < 4; j++)
        bfp[j] = Bt + (size_t)(bn + wn * 64 + j * 16 + ln) * N_FEAT + qd * 8;

    const int offA0 = (wm * 32 + ln) * 40 + qd * 8;
    const int offA1 = (wm * 32 + 16 + ln) * 40 + qd * 8;

    floatx4 acc[2][4];
#pragma unroll
    for (int i = 0; i < 2; i++)
#pragma unroll
        for (int j = 0; j < 4; j++) acc[i][j] = (floatx4){0.f, 0.f, 0.f, 0.f};

    // prologue: stage A tile0 -> As[0]; A raw tile1 -> regs; B tiles 0,1 -> b0,b1
    {
        float4 a0 = *(const float4*)(apA);
        float4 a1 = *(const float4*)(apA + 4);
        uint4 pk;
        pk.x = packtrunc(a0.x, a0.y); pk.y = packtrunc(a0.z, a0.w);
        pk.z = packtrunc(a1.x, a1.y); pk.w = packtrunc(a1.z, a1.w);
        *(uint4*)&As[0][r0 * 40 + cs] = pk;
    }
    float4 pa0 = *(const float4*)(apA + 32);
    float4 pa1 = *(const float4*)(apA + 36);
    uint4 b0[4], b1[4];
#pragma unroll
    for (int j = 0; j < 4; j++) b0[j] = *(const uint4*)(bfp[j]);
#pragma unroll
    for (int j = 0; j < 4; j++) b1[j] = *(const uint4*)(bfp[j] + 32);
    lds_barrier();

#define G1_ITER(BUF, BR, kk) do { \
        bf16x8 af0 = *(const bf16x8*)(const void*)&As[BUF][offA0]; \
        bf16x8 af1 = *(const bf16x8*)(const void*)&As[BUF][offA1]; \
        if ((kk) + 1 < 64) { \
            uint4 pk; \
            pk.x = packtrunc(pa0.x, pa0.y); pk.y = packtrunc(pa0.z, pa0.w); \
            pk.z = packtrunc(pa1.x, pa1.y); pk.w = packtrunc(pa1.z, pa1.w); \
            *(uint4*)&As[(BUF) ^ 1][r0 * 40 + cs] = pk; \
        } \
        if ((kk) + 2 < 64) { \
            pa0 = *(const float4*)(apA + ((kk) + 2) * 32); \
            pa1 = *(const float4*)(apA + ((kk) + 2) * 32 + 4); \
        } \
        bf16x8 bfr0 = u4_to_bf(BR[0]), bfr1 = u4_to_bf(BR[1]); \
        bf16x8 bfr2 = u4_to_bf(BR[2]), bfr3 = u4_to_bf(BR[3]); \
        if ((kk) + 2 < 64) { \
            _Pragma("unroll") for (int j = 0; j < 4; j++) \
                BR[j] = *(const uint4*)(bfp[j] + ((kk) + 2) * 32); \
        } \
        acc[0][0] = __builtin_amdgcn_mfma_f32_16x16x32_bf16(af0, bfr0, acc[0][0], 0, 0, 0); \
        acc[0][1] = __builtin_amdgcn_mfma_f32_16x16x32_bf16(af0, bfr1, acc[0][1], 0, 0, 0); \
        acc[0][2] = __builtin_amdgcn_mfma_f32_16x16x32_bf16(af0, bfr2, acc[0][2], 0, 0, 0); \
        acc[0][3] = __builtin_amdgcn_mfma_f32_16x16x32_bf16(af0, bfr3, acc[0][3], 0, 0, 0); \
        acc[1][0] = __builtin_amdgcn_mfma_f32_16x16x32_bf16(af1, bfr0, acc[1][0], 0, 0, 0); \
        acc[1][1] = __builtin_amdgcn_mfma_f32_16x16x32_bf16(af1, bfr1, acc[1][1], 0, 0, 0); \
        acc[1][2] = __builtin_amdgcn_mfma_f32_16x16x32_bf16(af1, bfr2, acc[1][2], 0, 0, 0); \
        acc[1][3] = __builtin_amdgcn_mfma_f32_16x16x32_bf16(af1, bfr3, acc[1][3], 0, 0, 0); \
        if ((kk) + 1 < 64) lds_barrier(); \
    } while (0)

    for (int k = 0; k < 64; k += 2) {
        G1_ITER(0, b0, k);
        G1_ITER(1, b1, k + 1);
    }
#undef G1_ITER

    // C write
#pragma unroll
    for (int i = 0; i < 2; i++)
#pragma unroll
        for (int j = 0; j < 4; j++)
#pragma unroll
            for (int p = 0; p < 4; p++) {
                int m = bm + wm * 32 + i * 16 + qd * 4 + p;
                if (m < N_NODES) {
                    int n = bn + wn * 64 + j * 16 + ln;
                    C[(size_t)m * H1 + n] = f2bf(acc[i][j][p]);
                }
            }
    // fused a1s/a1d partial row-dots (this wave covers cols bn+wn*64 .. +63)
    float avs[4], avd[4];
#pragma unroll
    for (int j = 0; j < 4; j++) {
        int n = bn + wn * 64 + j * 16 + ln;
        avs[j] = atts[n];
        avd[j] = attd[n];
    }
#pragma unroll
    for (int i = 0; i < 2; i++)
#pragma unroll
        for (int p = 0; p < 4; p++) {
            float vs = 0.f, vd = 0.f;
#pragma unroll
            for (int j = 0; j < 4; j++) {
                vs += acc[i][j][p] * avs[j];
                vd += acc[i][j][p] * avd[j];
            }
#pragma unroll
            for (int msk = 1; msk < 16; msk <<= 1) {
                vs += __shfl_xor(vs, msk);
                vd += __shfl_xor(vd, msk);
            }
            if (ln == p) {
                int m = bm + wm * 32 + i * 16 + qd * 4 + p;
                if (m < N_NODES) {
                    unsafeAtomicAdd(a1s + m, vs);
                    unsafeAtomicAdd(a1d + m, vd);
                }
            }
        }
}

// ---- GEMM4: sum += (F - h3@W1^T)^2 ------------------------------------------
// Same structure as gemm1: A (h3bf) via LDS dbuf (no pack, already bf16);
// B (w1bf, 2MB L2-resident) fragment-direct with reg ping-pong. 64x128 tile,
// 5008 blocks; K=512 -> 16 steps. MSE epilogue against F.
__global__ __launch_bounds__(256, 5) void gemm4_mse(const unsigned short* __restrict__ Ah, // h3bf [20000,512]
                                                    const unsigned short* __restrict__ B,  // w1bf [2048,512]
                                                    const float* __restrict__ F,           // [20000,2048] fp32
                                                    float* __restrict__ partial) {
    __shared__ unsigned short As[2][64 * 40];
    __shared__ float red[256];
    const int blk = blockIdx.x;
    const int xcd = blk & 7, rr = blk >> 3;
    const int ntile = rr & 15, group = rr >> 4;
    const int stripe = group * 8 + xcd;
    if (stripe >= 313) return;
    const int bm = stripe * 64, bn = ntile * 128;
    const int t = threadIdx.x;
    const int lane = t & 63, w = t >> 6;
    const int wm = w >> 1, wn = w & 1;
    const int ln = lane & 15, qd = lane >> 4;
    const int r0 = t >> 2, cs = (t & 3) * 8;

    int gra = bm + r0; if (gra > N_NODES - 1) gra = N_NODES - 1;
    const unsigned short* apA = Ah + (size_t)gra * H1 + cs;

    const unsigned short* bfp[4];
#pragma unroll
    for (int j = 0; j < 4; j++)
        bfp[j] = B + (size_t)(bn + wn * 64 + j * 16 + ln) * H1 + qd * 8;

    const int offA0 = (wm * 32 + ln) * 40 + qd * 8;
    const int offA1 = (wm * 32 + 16 + ln) * 40 + qd * 8;

    floatx4 acc[2][4];
#pragma unroll
    for (int i = 0; i < 2; i++)
#pragma unroll
        for (int j = 0; j < 4; j++) acc[i][j] = (floatx4){0.f, 0.f, 0.f, 0.f};

    // prologue
    {
        uint4 pk = *(const uint4*)(apA);
        *(uint4*)&As[0][r0 * 40 + cs] = pk;
    }
    uint4 pa = *(const uint4*)(apA + 32);
    uint4 b0[4], b1[4];
#pragma unroll
    for (int j = 0; j < 4; j++) b0[j] = *(const uint4*)(bfp[j]);
#pragma unroll
    for (int j = 0; j < 4; j++) b1[j] = *(const uint4*)(bfp[j] + 32);
    lds_barrier();

#define G4_ITER(BUF, BR, kk) do { \
        bf16x8 af0 = *(const bf16x8*)(const void*)&As[BUF][offA0]; \
        bf16x8 af1 = *(const bf16x8*)(const void*)&As[BUF][offA1]; \
        if ((kk) + 1 < 16) { \
            *(uint4*)&As[(BUF) ^ 1][r0 * 40 + cs] = pa; \
        } \
        if ((kk) + 2 < 16) { \
            pa = *(const uint4*)(apA + ((kk) + 2) * 32); \
        } \
        bf16x8 bfr0 = u4_to_bf(BR[0]), bfr1 = u4_to_bf(BR[1]); \
        bf16x8 bfr2 = u4_to_bf(BR[2]), bfr3 = u4_to_bf(BR[3]); \
        if ((kk) + 2 < 16) { \
            _Pragma("unroll") for (int j = 0; j < 4; j++) \
                BR[j] = *(const uint4*)(bfp[j] + ((kk) + 2) * 32); \
        } \
        acc[0][0] = __builtin_amdgcn_mfma_f32_16x16x32_bf16(af0, bfr0, acc[0][0], 0, 0, 0); \
        acc[0][1] = __builtin_amdgcn_mfma_f32_16x16x32_bf16(af0, bfr1, acc[0][1], 0, 0, 0); \
        acc[0][2] = __builtin_amdgcn_mfma_f32_16x16x32_bf16(af0, bfr2, acc[0][2], 0, 0, 0); \
        acc[0][3] = __builtin_amdgcn_mfma_f32_16x16x32_bf16(af0, bfr3, acc[0][3], 0, 0, 0); \
        acc[1][0] = __builtin_amdgcn_mfma_f32_16x16x32_bf16(af1, bfr0, acc[1][0], 0, 0, 0); \
        acc[1][1] = __builtin_amdgcn_mfma_f32_16x16x32_bf16(af1, bfr1, acc[1][1], 0, 0, 0); \
        acc[1][2] = __builtin_amdgcn_mfma_f32_16x16x32_bf16(af1, bfr2, acc[1][2], 0, 0, 0); \
        acc[1][3] = __builtin_amdgcn_mfma_f32_16x16x32_bf16(af1, bfr3, acc[1][3], 0, 0, 0); \
        if ((kk) + 1 < 16) lds_barrier(); \
    } while (0)

    for (int k = 0; k < 16; k += 2) {
        G4_ITER(0, b0, k);
        G4_ITER(1, b1, k + 1);
    }
#undef G4_ITER

    float sum = 0.f;
#pragma unroll
    for (int i = 0; i < 2; i++)
#pragma unroll
        for (int j = 0; j < 4; j++)
#pragma unroll
            for (int p = 0; p < 4; p++) {
                int m = bm + wm * 32 + i * 16 + qd * 4 + p;
                if (m < N_NODES) {
                    int n = bn + wn * 64 + j * 16 + ln;
                    float fv = F[(size_t)m * N_FEAT + n];
                    float d = fv - acc[i][j][p];
                    sum += d * d;
                }
            }
    red[t] = sum;
    __syncthreads();
    for (int off = 128; off; off >>= 1) {
        if (t < off) red[t] += red[t + off];
        __syncthreads();
    }
    if (t == 0) unsafeAtomicAdd(partial, red[0]);
}

// ---- edge pass --------------------------------------------------------------
__global__ void edge_att(const int* __restrict__ ei,
                         const float* __restrict__ a1s,
                         const float* __restrict__ a1d,
                         float* __restrict__ ebuf,
                         float* __restrict__ den,
                         int* __restrict__ deg) {
    int e = blockIdx.x * blockDim.x + threadIdx.x;
    if (e >= E_TOT) return;
    int s, d;
    if (e < N_EDGESI) { s = ei[e]; d = ei[N_EDGESI + e]; }
    else { s = e - N_EDGESI; d = s; }
    float x = a1s[s] + a1d[d];
    float sig = 1.f / (1.f + __expf(-x));
    float ex = __expf(sig);
    ebuf[e] = ex;
    unsafeAtomicAdd(&den[d], ex);
    atomicAdd(&deg[d], 1);
}

// ---- exclusive prefix sum over deg -> off (wave-shuffle scan) ---------------
__global__ __launch_bounds__(1024) void scan_k(const int* __restrict__ deg,
                                               int* __restrict__ off) {
    __shared__ int wsum[16];
    __shared__ int carry_s;
    const int lane = threadIdx.x & 63, wid = threadIdx.x >> 6;
    if (threadIdx.x == 0) carry_s = 0;
    __syncthreads();
    for (int base = 0; base < N_NODES; base += 1024) {
        int i = base + threadIdx.x;
        int v = (i < N_NODES) ? deg[i] : 0;
        int x = v;
#pragma unroll
        for (int s = 1; s < 64; s <<= 1) {
            int tt = __shfl_up(x, s);
            if (lane >= s) x += tt;
        }
        if (lane == 63) wsum[wid] = x;
        __syncthreads();
        if (wid == 0 && lane < 16) {
            int wv = wsum[lane];
#pragma unroll
            for (int s = 1; s < 16; s <<= 1) {
                int tt = __shfl_up(wv, s);
                if (lane >= s) wv += tt;
            }
            wsum[lane] = wv;
        }
        __syncthreads();
        int wbase = (wid == 0) ? 0 : wsum[wid - 1];
        int c = carry_s;
        int incl = x + wbase + c;
        if (i < N_NODES) off[i] = incl - v;
        __syncthreads();
        if (threadIdx.x == 0) carry_s = c + wsum[15];
        __syncthreads();
    }
}

// ---- bucket edges into CSR slots -------------------------------------------
__global__ void bucket_k(const int* __restrict__ ei,
                         const float* __restrict__ ebuf,
                         const float* __restrict__ den,
                         int* __restrict__ cursor,
                         int* __restrict__ csr_src,
                         float* __restrict__ csr_coef) {
    int e = blockIdx.x * blockDim.x + threadIdx.x;
    if (e >= E_TOT) return;
    int s, d;
    if (e < N_EDGESI) { s = ei[e]; d = ei[N_EDGESI + e]; }
    else { s = e - N_EDGESI; d = s; }
    int pos = atomicAdd(&cursor[d], 1);
    csr_src[pos] = s;
    csr_coef[pos] = ebuf[e] / den[d];
}

// ---- gather (bf16): Y[d] = elu(sum coef * X[src]), unroll-2 dual acc --------
__global__ __launch_bounds__(256) void gather_elu_bf(const int* __restrict__ off,
                                                     const int* __restrict__ csr_src,
                                                     const float* __restrict__ csr_coef,
                                                     const unsigned short* __restrict__ X,
                                                     unsigned short* __restrict__ Y) {
    int d = blockIdx.x * 4 + (threadIdx.x >> 6);
    int lane = threadIdx.x & 63;
    if (d >= N_NODES) return;
    int beg = off[d];
    int end = (d == N_NODES - 1) ? E_TOT : off[d + 1];
    float a[8] = {0.f, 0.f, 0.f, 0.f, 0.f, 0.f, 0.f, 0.f};
    float b[8] = {0.f, 0.f, 0.f, 0.f, 0.f, 0.f, 0.f, 0.f};
    int j = beg;
    for (; j + 1 < end; j += 2) {
        int s0 = csr_src[j], s1 = csr_src[j + 1];
        float c0 = csr_coef[j], c1 = csr_coef[j + 1];
        uint4 raw0 = *(const uint4*)(X + (size_t)s0 * H1 + lane * 8);
        uint4 raw1 = *(const uint4*)(X + (size_t)s1 * H1 + lane * 8);
        a[0] += __uint_as_float(raw0.x << 16) * c0;
        a[1] += __uint_as_float(raw0.x & 0xFFFF0000u) * c0;
        a[2] += __uint_as_float(raw0.y << 16) * c0;
        a[3] += __uint_as_float(raw0.y & 0xFFFF0000u) * c0;
        a[4] += __uint_as_float(raw0.z << 16) * c0;
        a[5] += __uint_as_float(raw0.z & 0xFFFF0000u) * c0;
        a[6] += __uint_as_float(raw0.w << 16) * c0;
        a[7] += __uint_as_float(raw0.w & 0xFFFF0000u) * c0;
        b[0] += __uint_as_float(raw1.x << 16) * c1;
        b[1] += __uint_as_float(raw1.x & 0xFFFF0000u) * c1;
        b[2] += __uint_as_float(raw1.y << 16) * c1;
        b[3] += __uint_as_float(raw1.y & 0xFFFF0000u) * c1;
        b[4] += __uint_as_float(raw1.z << 16) * c1;
        b[5] += __uint_as_float(raw1.z & 0xFFFF0000u) * c1;
        b[6] += __uint_as_float(raw1.w << 16) * c1;
        b[7] += __uint_as_float(raw1.w & 0xFFFF0000u) * c1;
    }
    if (j < end) {
        int s0 = csr_src[j];
        float c0 = csr_coef[j];
        uint4 raw0 = *(const uint4*)(X + (size_t)s0 * H1 + lane * 8);
        a[0] += __uint_as_float(raw0.x << 16) * c0;
        a[1] += __uint_as_float(raw0.x & 0xFFFF0000u) * c0;
        a[2] += __uint_as_float(raw0.y << 16) * c0;
        a[3] += __uint_as_float(raw0.y & 0xFFFF0000u) * c0;
        a[4] += __uint_as_float(raw0.z << 16) * c0;
        a[5] += __uint_as_float(raw0.z & 0xFFFF0000u) * c0;
        a[6] += __uint_as_float(raw0.w << 16) * c0;
        a[7] += __uint_as_float(raw0.w & 0xFFFF0000u) * c0;
    }
#pragma unroll
    for (int e = 0; e < 8; e++) {
        float v = a[e] + b[e];
        a[e] = v > 0.f ? v : __expf(v) - 1.f;
    }
    uint4 o;
    o.x = packrne(a[0], a[1]);
    o.y = packrne(a[2], a[3]);
    o.z = packrne(a[4], a[5]);
    o.w = packrne(a[6], a[7]);
    *(uint4*)(Y + (size_t)d * H1 + lane * 8) = o;
}

// ---- h2 = normalize_rows(h1 @ W2), h1 in bf16 -------------------------------
__global__ __launch_bounds__(256) void gemm2_norm_bf(const unsigned short* __restrict__ H1b,
                                                     const float* __restrict__ W2,
                                                     float* __restrict__ h2n) {
    __shared__ float hs[8 * 516];
    const int n0 = blockIdx.x * 8;
    const int tid = threadIdx.x;
    for (int idx = tid; idx < 512; idx += 256) {
        int r = idx >> 6, c = (idx & 63) * 8;
        uint4 raw = *(const uint4*)(H1b + (size_t)(n0 + r) * H1 + c);
        float* hp = hs + r * 516 + c;
        hp[0] = __uint_as_float(raw.x << 16);
        hp[1] = __uint_as_float(raw.x & 0xFFFF0000u);
        hp[2] = __uint_as_float(raw.y << 16);
        hp[3] = __uint_as_float(raw.y & 0xFFFF0000u);
        hp[4] = __uint_as_float(raw.z << 16);
        hp[5] = __uint_as_float(raw.z & 0xFFFF0000u);
        hp[6] = __uint_as_float(raw.w << 16);
        hp[7] = __uint_as_float(raw.w & 0xFFFF0000u);
    }
    __syncthreads();
    const int sub = tid >> 5, j = tid & 31;
    float a0 = 0.f, a1 = 0.f, a2 = 0.f, a3 = 0.f;
    if (j < H2) {
        const float* hr = hs + sub * 516;
        for (int k = 0; k < H1; k += 4) {
            a0 += hr[k] * W2[k * H2 + j];
            a1 += hr[k + 1] * W2[(k + 1) * H2 + j];
            a2 += hr[k + 2] * W2[(k + 2) * H2 + j];
            a3 += hr[k + 3] * W2[(k + 3) * H2 + j];
        }
    }
    float acc = (a0 + a1) + (a2 + a3);
    float sq = acc * acc;
    for (int m = 16; m; m >>= 1) sq += __shfl_xor(sq, m, 32);
    float inv = 1.f / fmaxf(sqrtf(sq), 1e-12f);
    if (j < H2) h2n[(size_t)(n0 + sub) * H2 + j] = acc * inv;
}

// ---- xw3 = h2n @ W2^T -> bf16 (W2 rows in registers, h2n scalar-broadcast) --
#define G3_CHUNK 40
__global__ __launch_bounds__(256) void gemm3_k(const float* __restrict__ h2n,
                                               const float* __restrict__ W2,
                                               unsigned short* __restrict__ xw3) {
    const int t = threadIdx.x;
    const int h0 = t << 1;             // columns h0, h0+1 of [0,512)
    float w0[H2], w1[H2];
#pragma unroll
    for (int k = 0; k < H2; k++) {
        w0[k] = W2[(size_t)h0 * H2 + k];
        w1[k] = W2[(size_t)h0 * H2 + H2 + k];
    }
    const int n0 = blockIdx.x * G3_CHUNK;
    const int nend = (n0 + G3_CHUNK < N_NODES) ? n0 + G3_CHUNK : N_NODES;
    for (int n = n0; n < nend; n++) {
        const float* hr = h2n + (size_t)n * H2;
        float a0 = 0.f, a1 = 0.f;
#pragma unroll
        for (int k = 0; k < H2; k++) {
            float hv = hr[k];
            a0 += hv * w0[k];
            a1 += hv * w1[k];
        }
        *(unsigned int*)(xw3 + (size_t)n * H1 + h0) = packrne(a0, a1);
    }
}

__global__ void finalize_k(const float* __restrict__ partial, float* __restrict__ out) {
    out[0] = partial[0] * (1.f / ((float)N_NODES * (float)N_FEAT));
}

extern "C" void kernel_launch(void* const* d_in, const int* in_sizes, int n_in,
                              void* d_out, int out_size, void* d_ws, size_t ws_size,
                              hipStream_t stream) {
    const float* features = (const float*)d_in[0];
    const int*   ei       = (const int*)d_in[1];
    const float* W1       = (const float*)d_in[2];
    const float* atts     = (const float*)d_in[3];
    const float* attd     = (const float*)d_in[4];
    const float* W2       = (const float*)d_in[5];
    float* out = (float*)d_out;

    char* ws = (char*)d_ws;
    unsigned short* xw1bf = (unsigned short*)(ws);              // 20,480,000 B (also xw3bf)
    unsigned short* h3bf  = (unsigned short*)(ws + 20480000);   // 20,480,000 B
    unsigned short* h1bf  = (unsigned short*)(ws + 40960000);   // 20,480,000 B
    unsigned short* w1bf  = (unsigned short*)(ws + 61440000);   //  2,097,152 B
    unsigned short* w1tbf = (unsigned short*)(ws + 63537152);   //  2,097,152 B
    float* h2n      = (float*)(ws + 65634304);                  //  2,400,000 B
    // zero region (single memset): a1s,a1d,den,deg,partial
    float* a1s      = (float*)(ws + 68034304);                  // 80,000
    float* a1d      = (float*)(ws + 68114304);                  // 80,000
    float* den      = (float*)(ws + 68194304);                  // 80,000
    int*   deg      = (int*)  (ws + 68274304);                  // 80,000
    float* partial  = (float*)(ws + 68354304);                  // 16
    float* ebuf     = (float*)(ws + 68354320);                  // 880,000
    int*   off      = (int*)  (ws + 69234320);
    int*   cursor   = (int*)  (ws + 69314320);
    int*   csr_src  = (int*)  (ws + 69394320);                  // 880,000
    float* csr_coef = (float*)(ws + 70274320);                  // 880,000

    hipMemsetAsync(a1s, 0, 320016, stream);  // a1s,a1d,den,deg,partial

    // 0) W1 -> bf16 (straight + transposed)
    cvtW1<<<dim3(16, 64), 256, 0, stream>>>(W1, w1bf, w1tbf);

    // 1) xw1 = features @ W1 (A via LDS dbuf, B fragment-direct) + a1s/a1d
    gemm1_mfma<<<1280, 256, 0, stream>>>(features, w1tbf, xw1bf, atts, attd, a1s, a1d);

    // 2) edge attention numerators + denominators + degree counts
    edge_att<<<(E_TOT + 255) / 256, 256, 0, stream>>>(ei, a1s, a1d, ebuf, den, deg);

    // 3) CSR build
    scan_k<<<1, 1024, 0, stream>>>(deg, off);
    hipMemcpyAsync(cursor, off, 20000 * 4, hipMemcpyDeviceToDevice, stream);
    bucket_k<<<(E_TOT + 255) / 256, 256, 0, stream>>>(ei, ebuf, den, cursor, csr_src, csr_coef);

    // 4) h1 = elu(gather(xw1))
    gather_elu_bf<<<N_NODES / 4, 256, 0, stream>>>(off, csr_src, csr_coef, xw1bf, h1bf);

    // 5) h2n = normalize_rows(h1 @ W2)
    gemm2_norm_bf<<<N_NODES / 8, 256, 0, stream>>>(h1bf, W2, h2n);

    // 6) xw3 = h2n @ W2^T (bf16 out, reuses xw1bf buffer)
    gemm3_k<<<(N_NODES + G3_CHUNK - 1) / G3_CHUNK, 256, 0, stream>>>(h2n, W2, xw1bf);

    // 7) h3 = elu(gather(xw3))
    gather_elu_bf<<<N_NODES / 4, 256, 0, stream>>>(off, csr_src, csr_coef, xw1bf, h3bf);

    // 8) fused h4 = h3 @ W1^T with MSE (A via LDS dbuf, B fragment-direct)
    gemm4_mse<<<5120, 256, 0, stream>>>(h3bf, w1bf, features, partial);

    // 9) finalize
    finalize_k<<<1, 1, 0, stream>>>(partial, out);
}

// Round 7
// 765.009 us; speedup vs baseline: 1.2767x; 1.2767x over previous
//
#include <hip/hip_runtime.h>
#include <math.h>

#define N_NODES 20000
#define N_EDGESI 200000
#define E_TOT   220000
#define N_FEAT  2048
#define H1      512
#define H2      30

typedef __bf16 bf16x8 __attribute__((ext_vector_type(8)));
typedef float  floatx4 __attribute__((ext_vector_type(4)));

// LDS-only barrier (no vmcnt drain): prefetch loads stay in flight across it.
__device__ __forceinline__ void lds_barrier() {
    asm volatile("s_waitcnt lgkmcnt(0)" ::: "memory");
    __builtin_amdgcn_s_barrier();
}

__device__ __forceinline__ unsigned short f2bf(float f) {   // RNE
    unsigned int u = __float_as_uint(f);
    unsigned int r = (u + 0x7FFF + ((u >> 16) & 1)) >> 16;
    return (unsigned short)r;
}
__device__ __forceinline__ unsigned int packtrunc(float a, float b) {
    return (__float_as_uint(a) >> 16) | (__float_as_uint(b) & 0xFFFF0000u);
}
__device__ __forceinline__ unsigned int packrne(float a, float b) {
    return (unsigned int)f2bf(a) | ((unsigned int)f2bf(b) << 16);
}
__device__ __forceinline__ bf16x8 u4_to_bf(uint4 u) {   // pure bit-reinterpret
    union { uint4 u; bf16x8 b; } cv; cv.u = u; return cv.b;
}

// ---- W1 conversion: w1bf[k][n] (straight) + w1tbf[n][k] (transposed) -------
__global__ __launch_bounds__(256) void cvtW1(const float* __restrict__ W1,
                                             unsigned short* __restrict__ w1bf,
                                             unsigned short* __restrict__ w1tbf) {
    __shared__ float tile[32][33];
    const int bk = blockIdx.y * 32, bn = blockIdx.x * 32;
    const int tc = threadIdx.x & 31, tr = threadIdx.x >> 5;  // 8 rows/pass
    for (int r = tr; r < 32; r += 8) {
        float v = W1[(size_t)(bk + r) * H1 + bn + tc];
        w1bf[(size_t)(bk + r) * H1 + bn + tc] = f2bf(v);
        tile[r][tc] = v;
    }
    __syncthreads();
    for (int r = tr; r < 32; r += 8) {
        w1tbf[(size_t)(bn + r) * N_FEAT + bk + tc] = f2bf(tile[tc][r]);
    }
}

// ---- GEMM1: xw1 = features @ W1 --------------------------------------------
// A (HBM-heavy, fp32) staged in LDS (dbuf, reg-prefetch+pack, R3 structure).
// B (2MB, L2-resident with XCD swizzle) loaded fragment-direct into registers
// (16B contiguous per lane), single set bc0..bc3, prefetched 1 iter ahead.
// Register-lean: no macros, no reg arrays, launch_bounds(256,4) so the
// allocator has a 128-VGPR budget (R6's (256,5)=102 caused a spill cascade:
// VGPR=48, 687MB scratch writes). u4_to_bf is a free bit-cast (B already bf16).
__global__ __launch_bounds__(256, 4) void gemm1_mfma(const float* __restrict__ A,          // [20000,2048] fp32
                                                     const unsigned short* __restrict__ Bt, // [512,2048] bf16
                                                     unsigned short* __restrict__ C,        // [20000,512] bf16
                                                     const float* __restrict__ atts,
                                                     const float* __restrict__ attd,
                                                     float* __restrict__ a1s,
                                                     float* __restrict__ a1d) {
    __shared__ unsigned short As[2][64 * 40];
    const int blk = blockIdx.x;
    const int xcd = blk & 7, rr = blk >> 3;
    const int ntile = rr & 3, group = rr >> 2;
    const int stripe = group * 8 + xcd;
    if (stripe >= 313) return;
    const int bm = stripe * 64, bn = ntile * 128;
    const int t = threadIdx.x;
    const int lane = t & 63, w = t >> 6;
    const int wm = w >> 1, wn = w & 1;          // wave: rows wm*32..+31, cols wn*64..+63
    const int ln = lane & 15, qd = lane >> 4;
    const int r0 = t >> 2, cs = (t & 3) * 8;    // A staging slice

    int gra = bm + r0; if (gra > N_NODES - 1) gra = N_NODES - 1;
    const float* apA = A + (size_t)gra * N_FEAT + cs;

    const unsigned short* bfp0 = Bt + (size_t)(bn + wn * 64 + 0  + ln) * N_FEAT + qd * 8;
    const unsigned short* bfp1 = Bt + (size_t)(bn + wn * 64 + 16 + ln) * N_FEAT + qd * 8;
    const unsigned short* bfp2 = Bt + (size_t)(bn + wn * 64 + 32 + ln) * N_FEAT + qd * 8;
    const unsigned short* bfp3 = Bt + (size_t)(bn + wn * 64 + 48 + ln) * N_FEAT + qd * 8;

    const int offA0 = (wm * 32 + ln) * 40 + qd * 8;
    const int offA1 = (wm * 32 + 16 + ln) * 40 + qd * 8;

    floatx4 acc[2][4];
#pragma unroll
    for (int i = 0; i < 2; i++)
#pragma unroll
        for (int j = 0; j < 4; j++) acc[i][j] = (floatx4){0.f, 0.f, 0.f, 0.f};

    // prologue: stage A tile0 -> As[0]; A raw tile1 -> regs; B tile0 -> bc
    {
        float4 a0 = *(const float4*)(apA);
        float4 a1 = *(const float4*)(apA + 4);
        uint4 pk;
        pk.x = packtrunc(a0.x, a0.y); pk.y = packtrunc(a0.z, a0.w);
        pk.z = packtrunc(a1.x, a1.y); pk.w = packtrunc(a1.z, a1.w);
        *(uint4*)&As[0][r0 * 40 + cs] = pk;
    }
    float4 pa0 = *(const float4*)(apA + 32);
    float4 pa1 = *(const float4*)(apA + 36);
    uint4 bc0 = *(const uint4*)(bfp0);
    uint4 bc1 = *(const uint4*)(bfp1);
    uint4 bc2 = *(const uint4*)(bfp2);
    uint4 bc3 = *(const uint4*)(bfp3);
    lds_barrier();

    int cur = 0;
    for (int k = 0; k < 64; ++k) {
        // A fragments from LDS
        bf16x8 af0 = *(const bf16x8*)(const void*)&As[cur][offA0];
        bf16x8 af1 = *(const bf16x8*)(const void*)&As[cur][offA1];
        // stage A tile k+1 (in regs since last iter) into the other buffer
        if (k + 1 < 64) {
            uint4 pk;
            pk.x = packtrunc(pa0.x, pa0.y); pk.y = packtrunc(pa0.z, pa0.w);
            pk.z = packtrunc(pa1.x, pa1.y); pk.w = packtrunc(pa1.z, pa1.w);
            *(uint4*)&As[cur ^ 1][r0 * 40 + cs] = pk;
        }
        // prefetch A tile k+2
        if (k + 2 < 64) {
            pa0 = *(const float4*)(apA + (k + 2) * 32);
            pa1 = *(const float4*)(apA + (k + 2) * 32 + 4);
        }
        // B fragments: reinterpret current regs, then refill for k+1
        bf16x8 bf0 = u4_to_bf(bc0), bf1 = u4_to_bf(bc1);
        bf16x8 bf2 = u4_to_bf(bc2), bf3 = u4_to_bf(bc3);
        if (k + 1 < 64) {
            const int kn = (k + 1) * 32;
            bc0 = *(const uint4*)(bfp0 + kn);
            bc1 = *(const uint4*)(bfp1 + kn);
            bc2 = *(const uint4*)(bfp2 + kn);
            bc3 = *(const uint4*)(bfp3 + kn);
        }
        acc[0][0] = __builtin_amdgcn_mfma_f32_16x16x32_bf16(af0, bf0, acc[0][0], 0, 0, 0);
        acc[0][1] = __builtin_amdgcn_mfma_f32_16x16x32_bf16(af0, bf1, acc[0][1], 0, 0, 0);
        acc[0][2] = __builtin_amdgcn_mfma_f32_16x16x32_bf16(af0, bf2, acc[0][2], 0, 0, 0);
        acc[0][3] = __builtin_amdgcn_mfma_f32_16x16x32_bf16(af0, bf3, acc[0][3], 0, 0, 0);
        acc[1][0] = __builtin_amdgcn_mfma_f32_16x16x32_bf16(af1, bf0, acc[1][0], 0, 0, 0);
        acc[1][1] = __builtin_amdgcn_mfma_f32_16x16x32_bf16(af1, bf1, acc[1][1], 0, 0, 0);
        acc[1][2] = __builtin_amdgcn_mfma_f32_16x16x32_bf16(af1, bf2, acc[1][2], 0, 0, 0);
        acc[1][3] = __builtin_amdgcn_mfma_f32_16x16x32_bf16(af1, bf3, acc[1][3], 0, 0, 0);
        if (k + 1 < 64) lds_barrier();
        cur ^= 1;
    }

    // C write
#pragma unroll
    for (int i = 0; i < 2; i++)
#pragma unroll
        for (int j = 0; j < 4; j++)
#pragma unroll
            for (int p = 0; p < 4; p++) {
                int m = bm + wm * 32 + i * 16 + qd * 4 + p;
                if (m < N_NODES) {
                    int n = bn + wn * 64 + j * 16 + ln;
                    C[(size_t)m * H1 + n] = f2bf(acc[i][j][p]);
                }
            }
    // fused a1s/a1d partial row-dots (this wave covers cols bn+wn*64 .. +63)
    float avs[4], avd[4];
#pragma unroll
    for (int j = 0; j < 4; j++) {
        int n = bn + wn * 64 + j * 16 + ln;
        avs[j] = atts[n];
        avd[j] = attd[n];
    }
#pragma unroll
    for (int i = 0; i < 2; i++)
#pragma unroll
        for (int p = 0; p < 4; p++) {
            float vs = 0.f, vd = 0.f;
#pragma unroll
            for (int j = 0; j < 4; j++) {
                vs += acc[i][j][p] * avs[j];
                vd += acc[i][j][p] * avd[j];
            }
#pragma unroll
            for (int msk = 1; msk < 16; msk <<= 1) {
                vs += __shfl_xor(vs, msk);
                vd += __shfl_xor(vd, msk);
            }
            if (ln == p) {
                int m = bm + wm * 32 + i * 16 + qd * 4 + p;
                if (m < N_NODES) {
                    unsafeAtomicAdd(a1s + m, vs);
                    unsafeAtomicAdd(a1d + m, vd);
                }
            }
        }
}

// ---- GEMM4: sum += (F - h3@W1^T)^2 ------------------------------------------
// Same structure: A (h3bf) via LDS dbuf (no pack, already bf16); B (w1bf,
// 2MB L2-resident) fragment-direct, single reg set, 1-ahead prefetch.
// 64x128 tile, 5008 working blocks, K=512 -> 16 steps. MSE epilogue vs F.
__global__ __launch_bounds__(256, 4) void gemm4_mse(const unsigned short* __restrict__ Ah, // h3bf [20000,512]
                                                    const unsigned short* __restrict__ B,  // w1bf [2048,512]
                                                    const float* __restrict__ F,           // [20000,2048] fp32
                                                    float* __restrict__ partial) {
    __shared__ unsigned short As[2][64 * 40];
    __shared__ float red[256];
    const int blk = blockIdx.x;
    const int xcd = blk & 7, rr = blk >> 3;
    const int ntile = rr & 15, group = rr >> 4;
    const int stripe = group * 8 + xcd;
    if (stripe >= 313) return;
    const int bm = stripe * 64, bn = ntile * 128;
    const int t = threadIdx.x;
    const int lane = t & 63, w = t >> 6;
    const int wm = w >> 1, wn = w & 1;
    const int ln = lane & 15, qd = lane >> 4;
    const int r0 = t >> 2, cs = (t & 3) * 8;

    int gra = bm + r0; if (gra > N_NODES - 1) gra = N_NODES - 1;
    const unsigned short* apA = Ah + (size_t)gra * H1 + cs;

    const unsigned short* bfp0 = B + (size_t)(bn + wn * 64 + 0  + ln) * H1 + qd * 8;
    const unsigned short* bfp1 = B + (size_t)(bn + wn * 64 + 16 + ln) * H1 + qd * 8;
    const unsigned short* bfp2 = B + (size_t)(bn + wn * 64 + 32 + ln) * H1 + qd * 8;
    const unsigned short* bfp3 = B + (size_t)(bn + wn * 64 + 48 + ln) * H1 + qd * 8;

    const int offA0 = (wm * 32 + ln) * 40 + qd * 8;
    const int offA1 = (wm * 32 + 16 + ln) * 40 + qd * 8;

    floatx4 acc[2][4];
#pragma unroll
    for (int i = 0; i < 2; i++)
#pragma unroll
        for (int j = 0; j < 4; j++) acc[i][j] = (floatx4){0.f, 0.f, 0.f, 0.f};

    // prologue
    {
        uint4 pk = *(const uint4*)(apA);
        *(uint4*)&As[0][r0 * 40 + cs] = pk;
    }
    uint4 pa = *(const uint4*)(apA + 32);
    uint4 bc0 = *(const uint4*)(bfp0);
    uint4 bc1 = *(const uint4*)(bfp1);
    uint4 bc2 = *(const uint4*)(bfp2);
    uint4 bc3 = *(const uint4*)(bfp3);
    lds_barrier();

    int cur = 0;
    for (int k = 0; k < 16; ++k) {
        bf16x8 af0 = *(const bf16x8*)(const void*)&As[cur][offA0];
        bf16x8 af1 = *(const bf16x8*)(const void*)&As[cur][offA1];
        if (k + 1 < 16) {
            *(uint4*)&As[cur ^ 1][r0 * 40 + cs] = pa;
        }
        if (k + 2 < 16) {
            pa = *(const uint4*)(apA + (k + 2) * 32);
        }
        bf16x8 bf0 = u4_to_bf(bc0), bf1 = u4_to_bf(bc1);
        bf16x8 bf2 = u4_to_bf(bc2), bf3 = u4_to_bf(bc3);
        if (k + 1 < 16) {
            const int kn = (k + 1) * 32;
            bc0 = *(const uint4*)(bfp0 + kn);
            bc1 = *(const uint4*)(bfp1 + kn);
            bc2 = *(const uint4*)(bfp2 + kn);
            bc3 = *(const uint4*)(bfp3 + kn);
        }
        acc[0][0] = __builtin_amdgcn_mfma_f32_16x16x32_bf16(af0, bf0, acc[0][0], 0, 0, 0);
        acc[0][1] = __builtin_amdgcn_mfma_f32_16x16x32_bf16(af0, bf1, acc[0][1], 0, 0, 0);
        acc[0][2] = __builtin_amdgcn_mfma_f32_16x16x32_bf16(af0, bf2, acc[0][2], 0, 0, 0);
        acc[0][3] = __builtin_amdgcn_mfma_f32_16x16x32_bf16(af0, bf3, acc[0][3], 0, 0, 0);
        acc[1][0] = __builtin_amdgcn_mfma_f32_16x16x32_bf16(af1, bf0, acc[1][0], 0, 0, 0);
        acc[1][1] = __builtin_amdgcn_mfma_f32_16x16x32_bf16(af1, bf1, acc[1][1], 0, 0, 0);
        acc[1][2] = __builtin_amdgcn_mfma_f32_16x16x32_bf16(af1, bf2, acc[1][2], 0, 0, 0);
        acc[1][3] = __builtin_amdgcn_mfma_f32_16x16x32_bf16(af1, bf3, acc[1][3], 0, 0, 0);
        if (k + 1 < 16) lds_barrier();
        cur ^= 1;
    }

    float sum = 0.f;
#pragma unroll
    for (int i = 0; i < 2; i++)
#pragma unroll
        for (int j = 0; j < 4; j++)
#pragma unroll
            for (int p = 0; p < 4; p++) {
                int m = bm + wm * 32 + i * 16 + qd * 4 + p;
                if (m < N_NODES) {
                    int n = bn + wn * 64 + j * 16 + ln;
                    float fv = F[(size_t)m * N_FEAT + n];
                    float d = fv - acc[i][j][p];
                    sum += d * d;
                }
            }
    red[t] = sum;
    __syncthreads();
    for (int off = 128; off; off >>= 1) {
        if (t < off) red[t] += red[t + off];
        __syncthreads();
    }
    if (t == 0) unsafeAtomicAdd(partial, red[0]);
}

// ---- edge pass --------------------------------------------------------------
__global__ void edge_att(const int* __restrict__ ei,
                         const float* __restrict__ a1s,
                         const float* __restrict__ a1d,
                         float* __restrict__ ebuf,
                         float* __restrict__ den,
                         int* __restrict__ deg) {
    int e = blockIdx.x * blockDim.x + threadIdx.x;
    if (e >= E_TOT) return;
    int s, d;
    if (e < N_EDGESI) { s = ei[e]; d = ei[N_EDGESI + e]; }
    else { s = e - N_EDGESI; d = s; }
    float x = a1s[s] + a1d[d];
    float sig = 1.f / (1.f + __expf(-x));
    float ex = __expf(sig);
    ebuf[e] = ex;
    unsafeAtomicAdd(&den[d], ex);
    atomicAdd(&deg[d], 1);
}

// ---- exclusive prefix sum over deg -> off (wave-shuffle scan) ---------------
__global__ __launch_bounds__(1024) void scan_k(const int* __restrict__ deg,
                                               int* __restrict__ off) {
    __shared__ int wsum[16];
    __shared__ int carry_s;
    const int lane = threadIdx.x & 63, wid = threadIdx.x >> 6;
    if (threadIdx.x == 0) carry_s = 0;
    __syncthreads();
    for (int base = 0; base < N_NODES; base += 1024) {
        int i = base + threadIdx.x;
        int v = (i < N_NODES) ? deg[i] : 0;
        int x = v;
#pragma unroll
        for (int s = 1; s < 64; s <<= 1) {
            int tt = __shfl_up(x, s);
            if (lane >= s) x += tt;
        }
        if (lane == 63) wsum[wid] = x;
        __syncthreads();
        if (wid == 0 && lane < 16) {
            int wv = wsum[lane];
#pragma unroll
            for (int s = 1; s < 16; s <<= 1) {
                int tt = __shfl_up(wv, s);
                if (lane >= s) wv += tt;
            }
            wsum[lane] = wv;
        }
        __syncthreads();
        int wbase = (wid == 0) ? 0 : wsum[wid - 1];
        int c = carry_s;
        int incl = x + wbase + c;
        if (i < N_NODES) off[i] = incl - v;
        __syncthreads();
        if (threadIdx.x == 0) carry_s = c + wsum[15];
        __syncthreads();
    }
}

// ---- bucket edges into CSR slots -------------------------------------------
__global__ void bucket_k(const int* __restrict__ ei,
                         const float* __restrict__ ebuf,
                         const float* __restrict__ den,
                         int* __restrict__ cursor,
                         int* __restrict__ csr_src,
                         float* __restrict__ csr_coef) {
    int e = blockIdx.x * blockDim.x + threadIdx.x;
    if (e >= E_TOT) return;
    int s, d;
    if (e < N_EDGESI) { s = ei[e]; d = ei[N_EDGESI + e]; }
    else { s = e - N_EDGESI; d = s; }
    int pos = atomicAdd(&cursor[d], 1);
    csr_src[pos] = s;
    csr_coef[pos] = ebuf[e] / den[d];
}

// ---- gather (bf16): Y[d] = elu(sum coef * X[src]), unroll-2 dual acc --------
__global__ __launch_bounds__(256) void gather_elu_bf(const int* __restrict__ off,
                                                     const int* __restrict__ csr_src,
                                                     const float* __restrict__ csr_coef,
                                                     const unsigned short* __restrict__ X,
                                                     unsigned short* __restrict__ Y) {
    int d = blockIdx.x * 4 + (threadIdx.x >> 6);
    int lane = threadIdx.x & 63;
    if (d >= N_NODES) return;
    int beg = off[d];
    int end = (d == N_NODES - 1) ? E_TOT : off[d + 1];
    float a[8] = {0.f, 0.f, 0.f, 0.f, 0.f, 0.f, 0.f, 0.f};
    float b[8] = {0.f, 0.f, 0.f, 0.f, 0.f, 0.f, 0.f, 0.f};
    int j = beg;
    for (; j + 1 < end; j += 2) {
        int s0 = csr_src[j], s1 = csr_src[j + 1];
        float c0 = csr_coef[j], c1 = csr_coef[j + 1];
        uint4 raw0 = *(const uint4*)(X + (size_t)s0 * H1 + lane * 8);
        uint4 raw1 = *(const uint4*)(X + (size_t)s1 * H1 + lane * 8);
        a[0] += __uint_as_float(raw0.x << 16) * c0;
        a[1] += __uint_as_float(raw0.x & 0xFFFF0000u) * c0;
        a[2] += __uint_as_float(raw0.y << 16) * c0;
        a[3] += __uint_as_float(raw0.y & 0xFFFF0000u) * c0;
        a[4] += __uint_as_float(raw0.z << 16) * c0;
        a[5] += __uint_as_float(raw0.z & 0xFFFF0000u) * c0;
        a[6] += __uint_as_float(raw0.w << 16) * c0;
        a[7] += __uint_as_float(raw0.w & 0xFFFF0000u) * c0;
        b[0] += __uint_as_float(raw1.x << 16) * c1;
        b[1] += __uint_as_float(raw1.x & 0xFFFF0000u) * c1;
        b[2] += __uint_as_float(raw1.y << 16) * c1;
        b[3] += __uint_as_float(raw1.y & 0xFFFF0000u) * c1;
        b[4] += __uint_as_float(raw1.z << 16) * c1;
        b[5] += __uint_as_float(raw1.z & 0xFFFF0000u) * c1;
        b[6] += __uint_as_float(raw1.w << 16) * c1;
        b[7] += __uint_as_float(raw1.w & 0xFFFF0000u) * c1;
    }
    if (j < end) {
        int s0 = csr_src[j];
        float c0 = csr_coef[j];
        uint4 raw0 = *(const uint4*)(X + (size_t)s0 * H1 + lane * 8);
        a[0] += __uint_as_float(raw0.x << 16) * c0;
        a[1] += __uint_as_float(raw0.x & 0xFFFF0000u) * c0;
        a[2] += __uint_as_float(raw0.y << 16) * c0;
        a[3] += __uint_as_float(raw0.y & 0xFFFF0000u) * c0;
        a[4] += __uint_as_float(raw0.z << 16) * c0;
        a[5] += __uint_as_float(raw0.z & 0xFFFF0000u) * c0;
        a[6] += __uint_as_float(raw0.w << 16) * c0;
        a[7] += __uint_as_float(raw0.w & 0xFFFF0000u) * c0;
    }
#pragma unroll
    for (int e = 0; e < 8; e++) {
        float v = a[e] + b[e];
        a[e] = v > 0.f ? v : __expf(v) - 1.f;
    }
    uint4 o;
    o.x = packrne(a[0], a[1]);
    o.y = packrne(a[2], a[3]);
    o.z = packrne(a[4], a[5]);
    o.w = packrne(a[6], a[7]);
    *(uint4*)(Y + (size_t)d * H1 + lane * 8) = o;
}

// ---- h2 = normalize_rows(h1 @ W2), h1 in bf16 -------------------------------
__global__ __launch_bounds__(256) void gemm2_norm_bf(const unsigned short* __restrict__ H1b,
                                                     const float* __restrict__ W2,
                                                     float* __restrict__ h2n) {
    __shared__ float hs[8 * 516];
    const int n0 = blockIdx.x * 8;
    const int tid = threadIdx.x;
    for (int idx = tid; idx < 512; idx += 256) {
        int r = idx >> 6, c = (idx & 63) * 8;
        uint4 raw = *(const uint4*)(H1b + (size_t)(n0 + r) * H1 + c);
        float* hp = hs + r * 516 + c;
        hp[0] = __uint_as_float(raw.x << 16);
        hp[1] = __uint_as_float(raw.x & 0xFFFF0000u);
        hp[2] = __uint_as_float(raw.y << 16);
        hp[3] = __uint_as_float(raw.y & 0xFFFF0000u);
        hp[4] = __uint_as_float(raw.z << 16);
        hp[5] = __uint_as_float(raw.z & 0xFFFF0000u);
        hp[6] = __uint_as_float(raw.w << 16);
        hp[7] = __uint_as_float(raw.w & 0xFFFF0000u);
    }
    __syncthreads();
    const int sub = tid >> 5, j = tid & 31;
    float a0 = 0.f, a1 = 0.f, a2 = 0.f, a3 = 0.f;
    if (j < H2) {
        const float* hr = hs + sub * 516;
        for (int k = 0; k < H1; k += 4) {
            a0 += hr[k] * W2[k * H2 + j];
            a1 += hr[k + 1] * W2[(k + 1) * H2 + j];
            a2 += hr[k + 2] * W2[(k + 2) * H2 + j];
            a3 += hr[k + 3] * W2[(k + 3) * H2 + j];
        }
    }
    float acc = (a0 + a1) + (a2 + a3);
    float sq = acc * acc;
    for (int m = 16; m; m >>= 1) sq += __shfl_xor(sq, m, 32);
    float inv = 1.f / fmaxf(sqrtf(sq), 1e-12f);
    if (j < H2) h2n[(size_t)(n0 + sub) * H2 + j] = acc * inv;
}

// ---- xw3 = h2n @ W2^T -> bf16 (W2 rows in registers, h2n scalar-broadcast) --
#define G3_CHUNK 40
__global__ __launch_bounds__(256) void gemm3_k(const float* __restrict__ h2n,
                                               const float* __restrict__ W2,
                                               unsigned short* __restrict__ xw3) {
    const int t = threadIdx.x;
    const int h0 = t << 1;             // columns h0, h0+1 of [0,512)
    float w0[H2], w1[H2];
#pragma unroll
    for (int k = 0; k < H2; k++) {
        w0[k] = W2[(size_t)h0 * H2 + k];
        w1[k] = W2[(size_t)h0 * H2 + H2 + k];
    }
    const int n0 = blockIdx.x * G3_CHUNK;
    const int nend = (n0 + G3_CHUNK < N_NODES) ? n0 + G3_CHUNK : N_NODES;
    for (int n = n0; n < nend; n++) {
        const float* hr = h2n + (size_t)n * H2;
        float a0 = 0.f, a1 = 0.f;
#pragma unroll
        for (int k = 0; k < H2; k++) {
            float hv = hr[k];
            a0 += hv * w0[k];
            a1 += hv * w1[k];
        }
        *(unsigned int*)(xw3 + (size_t)n * H1 + h0) = packrne(a0, a1);
    }
}

__global__ void finalize_k(const float* __restrict__ partial, float* __restrict__ out) {
    out[0] = partial[0] * (1.f / ((float)N_NODES * (float)N_FEAT));
}

extern "C" void kernel_launch(void* const* d_in, const int* in_sizes, int n_in,
                              void* d_out, int out_size, void* d_ws, size_t ws_size,
                              hipStream_t stream) {
    const float* features = (const float*)d_in[0];
    const int*   ei       = (const int*)d_in[1];
    const float* W1       = (const float*)d_in[2];
    const float* atts     = (const float*)d_in[3];
    const float* attd     = (const float*)d_in[4];
    const float* W2       = (const float*)d_in[5];
    float* out = (float*)d_out;

    char* ws = (char*)d_ws;
    unsigned short* xw1bf = (unsigned short*)(ws);              // 20,480,000 B (also xw3bf)
    unsigned short* h3bf  = (unsigned short*)(ws + 20480000);   // 20,480,000 B
    unsigned short* h1bf  = (unsigned short*)(ws + 40960000);   // 20,480,000 B
    unsigned short* w1bf  = (unsigned short*)(ws + 61440000);   //  2,097,152 B
    unsigned short* w1tbf = (unsigned short*)(ws + 63537152);   //  2,097,152 B
    float* h2n      = (float*)(ws + 65634304);                  //  2,400,000 B
    // zero region (single memset): a1s,a1d,den,deg,partial
    float* a1s      = (float*)(ws + 68034304);                  // 80,000
    float* a1d      = (float*)(ws + 68114304);                  // 80,000
    float* den      = (float*)(ws + 68194304);                  // 80,000
    int*   deg      = (int*)  (ws + 68274304);                  // 80,000
    float* partial  = (float*)(ws + 68354304);                  // 16
    float* ebuf     = (float*)(ws + 68354320);                  // 880,000
    int*   off      = (int*)  (ws + 69234320);
    int*   cursor   = (int*)  (ws + 69314320);
    int*   csr_src  = (int*)  (ws + 69394320);                  // 880,000
    float* csr_coef = (float*)(ws + 70274320);                  // 880,000

    hipMemsetAsync(a1s, 0, 320016, stream);  // a1s,a1d,den,deg,partial

    // 0) W1 -> bf16 (straight + transposed)
    cvtW1<<<dim3(16, 64), 256, 0, stream>>>(W1, w1bf, w1tbf);

    // 1) xw1 = features @ W1 (A via LDS dbuf, B fragment-direct) + a1s/a1d
    gemm1_mfma<<<1280, 256, 0, stream>>>(features, w1tbf, xw1bf, atts, attd, a1s, a1d);

    // 2) edge attention numerators + denominators + degree counts
    edge_att<<<(E_TOT + 255) / 256, 256, 0, stream>>>(ei, a1s, a1d, ebuf, den, deg);

    // 3) CSR build
    scan_k<<<1, 1024, 0, stream>>>(deg, off);
    hipMemcpyAsync(cursor, off, 20000 * 4, hipMemcpyDeviceToDevice, stream);
    bucket_k<<<(E_TOT + 255) / 256, 256, 0, stream>>>(ei, ebuf, den, cursor, csr_src, csr_coef);

    // 4) h1 = elu(gather(xw1))
    gather_elu_bf<<<N_NODES / 4, 256, 0, stream>>>(off, csr_src, csr_coef, xw1bf, h1bf);

    // 5) h2n = normalize_rows(h1 @ W2)
    gemm2_norm_bf<<<N_NODES / 8, 256, 0, stream>>>(h1bf, W2, h2n);

    // 6) xw3 = h2n @ W2^T (bf16 out, reuses xw1bf buffer)
    gemm3_k<<<(N_NODES + G3_CHUNK - 1) / G3_CHUNK, 256, 0, stream>>>(h2n, W2, xw1bf);

    // 7) h3 = elu(gather(xw3))
    gather_elu_bf<<<N_NODES / 4, 256, 0, stream>>>(off, csr_src, csr_coef, xw1bf, h3bf);

    // 8) fused h4 = h3 @ W1^T with MSE (A via LDS dbuf, B fragment-direct)
    gemm4_mse<<<5120, 256, 0, stream>>>(h3bf, w1bf, features, partial);

    // 9) finalize
    finalize_k<<<1, 1, 0, stream>>>(partial, out);
}

// Round 8
// 598.858 us; speedup vs baseline: 1.6309x; 1.2774x over previous
//
#include <hip/hip_runtime.h>
#include <math.h>

#define N_NODES 20000
#define N_EDGESI 200000
#define E_TOT   220000
#define N_FEAT  2048
#define H1      512
#define H2      30

typedef __bf16 bf16x8 __attribute__((ext_vector_type(8)));
typedef float  floatx4 __attribute__((ext_vector_type(4)));

// LDS-only barrier (no vmcnt drain): prefetch loads stay in flight across it.
__device__ __forceinline__ void lds_barrier() {
    asm volatile("s_waitcnt lgkmcnt(0)" ::: "memory");
    __builtin_amdgcn_s_barrier();
}

__device__ __forceinline__ unsigned short f2bf(float f) {   // RNE
    unsigned int u = __float_as_uint(f);
    unsigned int r = (u + 0x7FFF + ((u >> 16) & 1)) >> 16;
    return (unsigned short)r;
}
__device__ __forceinline__ float bf2f(unsigned short u) {
    return __uint_as_float(((unsigned int)u) << 16);
}
__device__ __forceinline__ unsigned int packtrunc(float a, float b) {
    return (__float_as_uint(a) >> 16) | (__float_as_uint(b) & 0xFFFF0000u);
}
__device__ __forceinline__ unsigned int packrne(float a, float b) {
    return (unsigned int)f2bf(a) | ((unsigned int)f2bf(b) << 16);
}

// ---- W1 conversion: w1bf[k][n] (straight) + w1tbf[n][k] (transposed) -------
__global__ __launch_bounds__(256) void cvtW1(const float* __restrict__ W1,
                                             unsigned short* __restrict__ w1bf,
                                             unsigned short* __restrict__ w1tbf) {
    __shared__ float tile[32][33];
    const int bk = blockIdx.y * 32, bn = blockIdx.x * 32;
    const int tc = threadIdx.x & 31, tr = threadIdx.x >> 5;  // 8 rows/pass
    for (int r = tr; r < 32; r += 8) {
        float v = W1[(size_t)(bk + r) * H1 + bn + tc];
        w1bf[(size_t)(bk + r) * H1 + bn + tc] = f2bf(v);
        tile[r][tc] = v;
    }
    __syncthreads();
    for (int r = tr; r < 32; r += 8) {
        w1tbf[(size_t)(bn + r) * N_FEAT + bk + tc] = f2bf(tile[tc][r]);
    }
}

// ---- GEMM1 (proven R3/R4 structure): xw1 = features @ W1 --------------------
// 64x128 tile, dbuf LDS, reg-staged A (fp32->bf16 pack) + B, one lds_barrier
// per K-step, XCD-swizzled grid. NEW: fused sum(F^2) — the ntile==0 blocks
// stage every F element of their stripe exactly once, so squaring at stage
// time computes sum(F^2) for free (part of the gemm4 MSE decomposition).
__global__ __launch_bounds__(256, 5) void gemm1_mfma(const float* __restrict__ A,          // [20000,2048] fp32
                                                     const unsigned short* __restrict__ Bt, // [512,2048] bf16
                                                     unsigned short* __restrict__ C,        // [20000,512] bf16
                                                     const float* __restrict__ atts,
                                                     const float* __restrict__ attd,
                                                     float* __restrict__ a1s,
                                                     float* __restrict__ a1d,
                                                     double* __restrict__ pF2) {
    __shared__ unsigned short As[2][64 * 40];
    __shared__ unsigned short Bs[2][128 * 40];
    __shared__ float red[256];
    const int blk = blockIdx.x;
    const int xcd = blk & 7, rr = blk >> 3;
    const int ntile = rr & 3, group = rr >> 2;
    const int stripe = group * 8 + xcd;
    if (stripe >= 313) return;
    const int bm = stripe * 64, bn = ntile * 128;
    const int t = threadIdx.x;
    const int lane = t & 63, w = t >> 6;
    const int wm = w >> 1, wn = w & 1;          // wave: rows wm*32..+31, cols wn*64..+63
    const int ln = lane & 15, qd = lane >> 4;
    const int r0 = t >> 2, cs = (t & 3) * 8;    // staging slice

    int gra = bm + r0;        if (gra > N_NODES - 1) gra = N_NODES - 1;
    const float* ap0 = A + (size_t)gra * N_FEAT + cs;
    const unsigned short* bp0 = Bt + (size_t)(bn + r0) * N_FEAT + cs;
    const unsigned short* bp1 = Bt + (size_t)(bn + r0 + 64) * N_FEAT + cs;

    const bool fz = (ntile == 0) && (bm + r0 < N_NODES);
    float fsum = 0.f;

    floatx4 acc[2][4];
#pragma unroll
    for (int i = 0; i < 2; i++)
#pragma unroll
        for (int j = 0; j < 4; j++) acc[i][j] = (floatx4){0.f, 0.f, 0.f, 0.f};

    // prologue: tile 0 -> regs -> buf 0; then issue tile 1 loads
    float4 pa00 = *(const float4*)(ap0);
    float4 pa01 = *(const float4*)(ap0 + 4);
    uint4  pb0  = *(const uint4*)(bp0);
    uint4  pb1  = *(const uint4*)(bp1);
    {
        uint4 pk0;
        pk0.x = packtrunc(pa00.x, pa00.y); pk0.y = packtrunc(pa00.z, pa00.w);
        pk0.z = packtrunc(pa01.x, pa01.y); pk0.w = packtrunc(pa01.z, pa01.w);
        *(uint4*)&As[0][r0 * 40 + cs] = pk0;
        *(uint4*)&Bs[0][r0 * 40 + cs] = pb0;
        *(uint4*)&Bs[0][(r0 + 64) * 40 + cs] = pb1;
        if (fz) {
            fsum += pa00.x * pa00.x + pa00.y * pa00.y + pa00.z * pa00.z + pa00.w * pa00.w;
            fsum += pa01.x * pa01.x + pa01.y * pa01.y + pa01.z * pa01.z + pa01.w * pa01.w;
        }
    }
    pa00 = *(const float4*)(ap0 + 32);
    pa01 = *(const float4*)(ap0 + 36);
    pb0  = *(const uint4*)(bp0 + 32);
    pb1  = *(const uint4*)(bp1 + 32);
    lds_barrier();

    int cur = 0;
    for (int k0 = 0; k0 < N_FEAT; k0 += 32) {
        // 1) fragment reads from current buffer (issue first)
        bf16x8 af[2], bfr[4];
        const unsigned short* Ab = &As[cur][(wm * 32 + ln) * 40 + qd * 8];
        const unsigned short* Bb = &Bs[cur][(wn * 64 + ln) * 40 + qd * 8];
#pragma unroll
        for (int i = 0; i < 2; i++) af[i]  = *(const bf16x8*)(const void*)(Ab + i * 16 * 40);
#pragma unroll
        for (int j = 0; j < 4; j++) bfr[j] = *(const bf16x8*)(const void*)(Bb + j * 16 * 40);
        // 2) stage tile k0+32 (in regs since last iter) into the other buffer
        if (k0 + 32 < N_FEAT) {
            uint4 pk0;
            pk0.x = packtrunc(pa00.x, pa00.y); pk0.y = packtrunc(pa00.z, pa00.w);
            pk0.z = packtrunc(pa01.x, pa01.y); pk0.w = packtrunc(pa01.z, pa01.w);
            const int nb = cur ^ 1;
            *(uint4*)&As[nb][r0 * 40 + cs] = pk0;
            *(uint4*)&Bs[nb][r0 * 40 + cs] = pb0;
            *(uint4*)&Bs[nb][(r0 + 64) * 40 + cs] = pb1;
            if (fz) {
                fsum += pa00.x * pa00.x + pa00.y * pa00.y + pa00.z * pa00.z + pa00.w * pa00.w;
                fsum += pa01.x * pa01.x + pa01.y * pa01.y + pa01.z * pa01.z + pa01.w * pa01.w;
            }
            // 3) issue tile k0+64 global loads (stay in flight across barrier)
            if (k0 + 64 < N_FEAT) {
                const int kn = k0 + 64;
                pa00 = *(const float4*)(ap0 + kn);
                pa01 = *(const float4*)(ap0 + kn + 4);
                pb0  = *(const uint4*)(bp0 + kn);
                pb1  = *(const uint4*)(bp1 + kn);
            }
        }
        // 4) compute
#pragma unroll
        for (int i = 0; i < 2; i++)
#pragma unroll
            for (int j = 0; j < 4; j++)
                acc[i][j] = __builtin_amdgcn_mfma_f32_16x16x32_bf16(af[i], bfr[j], acc[i][j], 0, 0, 0);
        // 5) single LDS-only barrier per K-step
        if (k0 + 32 < N_FEAT) lds_barrier();
        cur ^= 1;
    }

    // C write
#pragma unroll
    for (int i = 0; i < 2; i++)
#pragma unroll
        for (int j = 0; j < 4; j++)
#pragma unroll
            for (int p = 0; p < 4; p++) {
                int m = bm + wm * 32 + i * 16 + qd * 4 + p;
                if (m < N_NODES) {
                    int n = bn + wn * 64 + j * 16 + ln;
                    C[(size_t)m * H1 + n] = f2bf(acc[i][j][p]);
                }
            }
    // fused a1s/a1d partial row-dots (this wave covers cols bn+wn*64 .. +63)
    float avs[4], avd[4];
#pragma unroll
    for (int j = 0; j < 4; j++) {
        int n = bn + wn * 64 + j * 16 + ln;
        avs[j] = atts[n];
        avd[j] = attd[n];
    }
#pragma unroll
    for (int i = 0; i < 2; i++)
#pragma unroll
        for (int p = 0; p < 4; p++) {
            float vs = 0.f, vd = 0.f;
#pragma unroll
            for (int j = 0; j < 4; j++) {
                vs += acc[i][j][p] * avs[j];
                vd += acc[i][j][p] * avd[j];
            }
#pragma unroll
            for (int msk = 1; msk < 16; msk <<= 1) {
                vs += __shfl_xor(vs, msk);
                vd += __shfl_xor(vd, msk);
            }
            if (ln == p) {
                int m = bm + wm * 32 + i * 16 + qd * 4 + p;
                if (m < N_NODES) {
                    unsafeAtomicAdd(a1s + m, vs);
                    unsafeAtomicAdd(a1d + m, vd);
                }
            }
        }
    // sum(F^2) block reduction (ntile==0 blocks only; block-uniform branch)
    if (ntile == 0) {
        red[t] = fsum;
        __syncthreads();
        for (int off = 128; off; off >>= 1) {
            if (t < off) red[t] += red[t + off];
            __syncthreads();
        }
        if (t == 0) unsafeAtomicAdd(pF2, (double)red[0]);
    }
}

// ---- GEMMG: G = W1^T W1 -> bf16 [512,512] (symmetric) -----------------------
// A = Bt = w1tbf [512,2048]. 64x128 tile, 8 stripes x 4 ntiles = 32 blocks,
// K=2048 -> 64 iters. Same dbuf/lds_barrier structure (A already bf16).
__global__ __launch_bounds__(256, 5) void gemmg_k(const unsigned short* __restrict__ Wt,
                                                  unsigned short* __restrict__ G) {
    __shared__ unsigned short As[2][64 * 40];
    __shared__ unsigned short Bs[2][128 * 40];
    const int stripe = blockIdx.x >> 2, ntile = blockIdx.x & 3;
    const int bm = stripe * 64, bn = ntile * 128;
    const int t = threadIdx.x;
    const int lane = t & 63, w = t >> 6;
    const int wm = w >> 1, wn = w & 1;
    const int ln = lane & 15, qd = lane >> 4;
    const int r0 = t >> 2, cs = (t & 3) * 8;

    const unsigned short* ap0 = Wt + (size_t)(bm + r0) * N_FEAT + cs;
    const unsigned short* bp0 = Wt + (size_t)(bn + r0) * N_FEAT + cs;
    const unsigned short* bp1 = Wt + (size_t)(bn + r0 + 64) * N_FEAT + cs;

    floatx4 acc[2][4];
#pragma unroll
    for (int i = 0; i < 2; i++)
#pragma unroll
        for (int j = 0; j < 4; j++) acc[i][j] = (floatx4){0.f, 0.f, 0.f, 0.f};

    uint4 pa  = *(const uint4*)(ap0);
    uint4 pb0 = *(const uint4*)(bp0);
    uint4 pb1 = *(const uint4*)(bp1);
    *(uint4*)&As[0][r0 * 40 + cs] = pa;
    *(uint4*)&Bs[0][r0 * 40 + cs] = pb0;
    *(uint4*)&Bs[0][(r0 + 64) * 40 + cs] = pb1;
    pa  = *(const uint4*)(ap0 + 32);
    pb0 = *(const uint4*)(bp0 + 32);
    pb1 = *(const uint4*)(bp1 + 32);
    lds_barrier();

    int cur = 0;
    for (int k0 = 0; k0 < N_FEAT; k0 += 32) {
        bf16x8 af[2], bfr[4];
        const unsigned short* Ab = &As[cur][(wm * 32 + ln) * 40 + qd * 8];
        const unsigned short* Bb = &Bs[cur][(wn * 64 + ln) * 40 + qd * 8];
#pragma unroll
        for (int i = 0; i < 2; i++) af[i]  = *(const bf16x8*)(const void*)(Ab + i * 16 * 40);
#pragma unroll
        for (int j = 0; j < 4; j++) bfr[j] = *(const bf16x8*)(const void*)(Bb + j * 16 * 40);
        if (k0 + 32 < N_FEAT) {
            const int nb = cur ^ 1;
            *(uint4*)&As[nb][r0 * 40 + cs] = pa;
            *(uint4*)&Bs[nb][r0 * 40 + cs] = pb0;
            *(uint4*)&Bs[nb][(r0 + 64) * 40 + cs] = pb1;
            if (k0 + 64 < N_FEAT) {
                const int kn = k0 + 64;
                pa  = *(const uint4*)(ap0 + kn);
                pb0 = *(const uint4*)(bp0 + kn);
                pb1 = *(const uint4*)(bp1 + kn);
            }
        }
#pragma unroll
        for (int i = 0; i < 2; i++)
#pragma unroll
            for (int j = 0; j < 4; j++)
                acc[i][j] = __builtin_amdgcn_mfma_f32_16x16x32_bf16(af[i], bfr[j], acc[i][j], 0, 0, 0);
        if (k0 + 32 < N_FEAT) lds_barrier();
        cur ^= 1;
    }
#pragma unroll
    for (int i = 0; i < 2; i++)
#pragma unroll
        for (int j = 0; j < 4; j++)
#pragma unroll
            for (int p = 0; p < 4; p++) {
                int m = bm + wm * 32 + i * 16 + qd * 4 + p;
                int n = bn + wn * 64 + j * 16 + ln;
                G[(size_t)m * H1 + n] = f2bf(acc[i][j][p]);
            }
}

// ---- GEMMQ: quad = sum_m h3[m] G h3[m]^T, cross = sum xw1 .* h3 -------------
// C2 = h3 @ G (G symmetric so Gbf rows serve as B^T). Instead of writing C2,
// the epilogue dots each element with h3 (quad) and also accumulates
// xw1 .* h3 (cross) at the same positions. Replaces the 42-GFLOP gemm4
// (10.5 GFLOP, no 164MB F re-read). Double atomics for cancellation safety.
__global__ __launch_bounds__(256, 5) void gemmq_k(const unsigned short* __restrict__ Ah,  // h3bf [20000,512]
                                                  const unsigned short* __restrict__ Gt,  // Gbf [512,512]
                                                  const unsigned short* __restrict__ XW1, // xw1bf [20000,512]
                                                  double* __restrict__ pcross,
                                                  double* __restrict__ pquad) {
    __shared__ unsigned short As[2][64 * 40];
    __shared__ unsigned short Bs[2][128 * 40];
    __shared__ float2 red2[256];
    const int blk = blockIdx.x;
    const int xcd = blk & 7, rr = blk >> 3;
    const int ntile = rr & 3, group = rr >> 2;
    const int stripe = group * 8 + xcd;
    if (stripe >= 313) return;
    const int bm = stripe * 64, bn = ntile * 128;
    const int t = threadIdx.x;
    const int lane = t & 63, w = t >> 6;
    const int wm = w >> 1, wn = w & 1;
    const int ln = lane & 15, qd = lane >> 4;
    const int r0 = t >> 2, cs = (t & 3) * 8;

    int gra = bm + r0; if (gra > N_NODES - 1) gra = N_NODES - 1;
    const unsigned short* ap0 = Ah + (size_t)gra * H1 + cs;
    const unsigned short* bp0 = Gt + (size_t)(bn + r0) * H1 + cs;
    const unsigned short* bp1 = Gt + (size_t)(bn + r0 + 64) * H1 + cs;

    floatx4 acc[2][4];
#pragma unroll
    for (int i = 0; i < 2; i++)
#pragma unroll
        for (int j = 0; j < 4; j++) acc[i][j] = (floatx4){0.f, 0.f, 0.f, 0.f};

    uint4 pa  = *(const uint4*)(ap0);
    uint4 pb0 = *(const uint4*)(bp0);
    uint4 pb1 = *(const uint4*)(bp1);
    *(uint4*)&As[0][r0 * 40 + cs] = pa;
    *(uint4*)&Bs[0][r0 * 40 + cs] = pb0;
    *(uint4*)&Bs[0][(r0 + 64) * 40 + cs] = pb1;
    pa  = *(const uint4*)(ap0 + 32);
    pb0 = *(const uint4*)(bp0 + 32);
    pb1 = *(const uint4*)(bp1 + 32);
    lds_barrier();

    int cur = 0;
    for (int k0 = 0; k0 < H1; k0 += 32) {
        bf16x8 af[2], bfr[4];
        const unsigned short* Ab = &As[cur][(wm * 32 + ln) * 40 + qd * 8];
        const unsigned short* Bb = &Bs[cur][(wn * 64 + ln) * 40 + qd * 8];
#pragma unroll
        for (int i = 0; i < 2; i++) af[i]  = *(const bf16x8*)(const void*)(Ab + i * 16 * 40);
#pragma unroll
        for (int j = 0; j < 4; j++) bfr[j] = *(const bf16x8*)(const void*)(Bb + j * 16 * 40);
        if (k0 + 32 < H1) {
            const int nb = cur ^ 1;
            *(uint4*)&As[nb][r0 * 40 + cs] = pa;
            *(uint4*)&Bs[nb][r0 * 40 + cs] = pb0;
            *(uint4*)&Bs[nb][(r0 + 64) * 40 + cs] = pb1;
            if (k0 + 64 < H1) {
                const int kn = k0 + 64;
                pa  = *(const uint4*)(ap0 + kn);
                pb0 = *(const uint4*)(bp0 + kn);
                pb1 = *(const uint4*)(bp1 + kn);
            }
        }
#pragma unroll
        for (int i = 0; i < 2; i++)
#pragma unroll
            for (int j = 0; j < 4; j++)
                acc[i][j] = __builtin_amdgcn_mfma_f32_16x16x32_bf16(af[i], bfr[j], acc[i][j], 0, 0, 0);
        if (k0 + 32 < H1) lds_barrier();
        cur ^= 1;
    }

    float qsum = 0.f, csum = 0.f;
#pragma unroll
    for (int i = 0; i < 2; i++)
#pragma unroll
        for (int j = 0; j < 4; j++)
#pragma unroll
            for (int p = 0; p < 4; p++) {
                int m = bm + wm * 32 + i * 16 + qd * 4 + p;
                if (m < N_NODES) {
                    int n = bn + wn * 64 + j * 16 + ln;
                    float h3v = bf2f(Ah[(size_t)m * H1 + n]);
                    float xv  = bf2f(XW1[(size_t)m * H1 + n]);
                    qsum += acc[i][j][p] * h3v;
                    csum += xv * h3v;
                }
            }
    red2[t].x = qsum; red2[t].y = csum;
    __syncthreads();
    for (int off = 128; off; off >>= 1) {
        if (t < off) { red2[t].x += red2[t + off].x; red2[t].y += red2[t + off].y; }
        __syncthreads();
    }
    if (t == 0) {
        unsafeAtomicAdd(pquad,  (double)red2[0].x);
        unsafeAtomicAdd(pcross, (double)red2[0].y);
    }
}

// ---- edge pass --------------------------------------------------------------
__global__ void edge_att(const int* __restrict__ ei,
                         const float* __restrict__ a1s,
                         const float* __restrict__ a1d,
                         float* __restrict__ ebuf,
                         float* __restrict__ den,
                         int* __restrict__ deg) {
    int e = blockIdx.x * blockDim.x + threadIdx.x;
    if (e >= E_TOT) return;
    int s, d;
    if (e < N_EDGESI) { s = ei[e]; d = ei[N_EDGESI + e]; }
    else { s = e - N_EDGESI; d = s; }
    float x = a1s[s] + a1d[d];
    float sig = 1.f / (1.f + __expf(-x));
    float ex = __expf(sig);
    ebuf[e] = ex;
    unsafeAtomicAdd(&den[d], ex);
    atomicAdd(&deg[d], 1);
}

// ---- exclusive prefix sum over deg -> off AND cursor ------------------------
__global__ __launch_bounds__(1024) void scan_k(const int* __restrict__ deg,
                                               int* __restrict__ off,
                                               int* __restrict__ cursor) {
    __shared__ int wsum[16];
    __shared__ int carry_s;
    const int lane = threadIdx.x & 63, wid = threadIdx.x >> 6;
    if (threadIdx.x == 0) carry_s = 0;
    __syncthreads();
    for (int base = 0; base < N_NODES; base += 1024) {
        int i = base + threadIdx.x;
        int v = (i < N_NODES) ? deg[i] : 0;
        int x = v;
#pragma unroll
        for (int s = 1; s < 64; s <<= 1) {
            int tt = __shfl_up(x, s);
            if (lane >= s) x += tt;
        }
        if (lane == 63) wsum[wid] = x;
        __syncthreads();
        if (wid == 0 && lane < 16) {
            int wv = wsum[lane];
#pragma unroll
            for (int s = 1; s < 16; s <<= 1) {
                int tt = __shfl_up(wv, s);
                if (lane >= s) wv += tt;
            }
            wsum[lane] = wv;
        }
        __syncthreads();
        int wbase = (wid == 0) ? 0 : wsum[wid - 1];
        int c = carry_s;
        int incl = x + wbase + c;
        if (i < N_NODES) { off[i] = incl - v; cursor[i] = incl - v; }
        __syncthreads();
        if (threadIdx.x == 0) carry_s = c + wsum[15];
        __syncthreads();
    }
}

// ---- bucket edges into CSR slots -------------------------------------------
__global__ void bucket_k(const int* __restrict__ ei,
                         const float* __restrict__ ebuf,
                         const float* __restrict__ den,
                         int* __restrict__ cursor,
                         int* __restrict__ csr_src,
                         float* __restrict__ csr_coef) {
    int e = blockIdx.x * blockDim.x + threadIdx.x;
    if (e >= E_TOT) return;
    int s, d;
    if (e < N_EDGESI) { s = ei[e]; d = ei[N_EDGESI + e]; }
    else { s = e - N_EDGESI; d = s; }
    int pos = atomicAdd(&cursor[d], 1);
    csr_src[pos] = s;
    csr_coef[pos] = ebuf[e] / den[d];
}

// ---- gather (bf16): Y[d] = elu(sum coef * X[src]), unroll-2 dual acc --------
__global__ __launch_bounds__(256) void gather_elu_bf(const int* __restrict__ off,
                                                     const int* __restrict__ csr_src,
                                                     const float* __restrict__ csr_coef,
                                                     const unsigned short* __restrict__ X,
                                                     unsigned short* __restrict__ Y) {
    int d = blockIdx.x * 4 + (threadIdx.x >> 6);
    int lane = threadIdx.x & 63;
    if (d >= N_NODES) return;
    int beg = off[d];
    int end = (d == N_NODES - 1) ? E_TOT : off[d + 1];
    float a[8] = {0.f, 0.f, 0.f, 0.f, 0.f, 0.f, 0.f, 0.f};
    float b[8] = {0.f, 0.f, 0.f, 0.f, 0.f, 0.f, 0.f, 0.f};
    int j = beg;
    for (; j + 1 < end; j += 2) {
        int s0 = csr_src[j], s1 = csr_src[j + 1];
        float c0 = csr_coef[j], c1 = csr_coef[j + 1];
        uint4 raw0 = *(const uint4*)(X + (size_t)s0 * H1 + lane * 8);
        uint4 raw1 = *(const uint4*)(X + (size_t)s1 * H1 + lane * 8);
        a[0] += __uint_as_float(raw0.x << 16) * c0;
        a[1] += __uint_as_float(raw0.x & 0xFFFF0000u) * c0;
        a[2] += __uint_as_float(raw0.y << 16) * c0;
        a[3] += __uint_as_float(raw0.y & 0xFFFF0000u) * c0;
        a[4] += __uint_as_float(raw0.z << 16) * c0;
        a[5] += __uint_as_float(raw0.z & 0xFFFF0000u) * c0;
        a[6] += __uint_as_float(raw0.w << 16) * c0;
        a[7] += __uint_as_float(raw0.w & 0xFFFF0000u) * c0;
        b[0] += __uint_as_float(raw1.x << 16) * c1;
        b[1] += __uint_as_float(raw1.x & 0xFFFF0000u) * c1;
        b[2] += __uint_as_float(raw1.y << 16) * c1;
        b[3] += __uint_as_float(raw1.y & 0xFFFF0000u) * c1;
        b[4] += __uint_as_float(raw1.z << 16) * c1;
        b[5] += __uint_as_float(raw1.z & 0xFFFF0000u) * c1;
        b[6] += __uint_as_float(raw1.w << 16) * c1;
        b[7] += __uint_as_float(raw1.w & 0xFFFF0000u) * c1;
    }
    if (j < end) {
        int s0 = csr_src[j];
        float c0 = csr_coef[j];
        uint4 raw0 = *(const uint4*)(X + (size_t)s0 * H1 + lane * 8);
        a[0] += __uint_as_float(raw0.x << 16) * c0;
        a[1] += __uint_as_float(raw0.x & 0xFFFF0000u) * c0;
        a[2] += __uint_as_float(raw0.y << 16) * c0;
        a[3] += __uint_as_float(raw0.y & 0xFFFF0000u) * c0;
        a[4] += __uint_as_float(raw0.z << 16) * c0;
        a[5] += __uint_as_float(raw0.z & 0xFFFF0000u) * c0;
        a[6] += __uint_as_float(raw0.w << 16) * c0;
        a[7] += __uint_as_float(raw0.w & 0xFFFF0000u) * c0;
    }
#pragma unroll
    for (int e = 0; e < 8; e++) {
        float v = a[e] + b[e];
        a[e] = v > 0.f ? v : __expf(v) - 1.f;
    }
    uint4 o;
    o.x = packrne(a[0], a[1]);
    o.y = packrne(a[2], a[3]);
    o.z = packrne(a[4], a[5]);
    o.w = packrne(a[6], a[7]);
    *(uint4*)(Y + (size_t)d * H1 + lane * 8) = o;
}

// ---- h2 = normalize_rows(h1 @ W2), h1 in bf16 -------------------------------
__global__ __launch_bounds__(256) void gemm2_norm_bf(const unsigned short* __restrict__ H1b,
                                                     const float* __restrict__ W2,
                                                     float* __restrict__ h2n) {
    __shared__ float hs[8 * 516];
    const int n0 = blockIdx.x * 8;
    const int tid = threadIdx.x;
    for (int idx = tid; idx < 512; idx += 256) {
        int r = idx >> 6, c = (idx & 63) * 8;
        uint4 raw = *(const uint4*)(H1b + (size_t)(n0 + r) * H1 + c);
        float* hp = hs + r * 516 + c;
        hp[0] = __uint_as_float(raw.x << 16);
        hp[1] = __uint_as_float(raw.x & 0xFFFF0000u);
        hp[2] = __uint_as_float(raw.y << 16);
        hp[3] = __uint_as_float(raw.y & 0xFFFF0000u);
        hp[4] = __uint_as_float(raw.z << 16);
        hp[5] = __uint_as_float(raw.z & 0xFFFF0000u);
        hp[6] = __uint_as_float(raw.w << 16);
        hp[7] = __uint_as_float(raw.w & 0xFFFF0000u);
    }
    __syncthreads();
    const int sub = tid >> 5, j = tid & 31;
    float a0 = 0.f, a1 = 0.f, a2 = 0.f, a3 = 0.f;
    if (j < H2) {
        const float* hr = hs + sub * 516;
        for (int k = 0; k < H1; k += 4) {
            a0 += hr[k] * W2[k * H2 + j];
            a1 += hr[k + 1] * W2[(k + 1) * H2 + j];
            a2 += hr[k + 2] * W2[(k + 2) * H2 + j];
            a3 += hr[k + 3] * W2[(k + 3) * H2 + j];
        }
    }
    float acc = (a0 + a1) + (a2 + a3);
    float sq = acc * acc;
    for (int m = 16; m; m >>= 1) sq += __shfl_xor(sq, m, 32);
    float inv = 1.f / fmaxf(sqrtf(sq), 1e-12f);
    if (j < H2) h2n[(size_t)(n0 + sub) * H2 + j] = acc * inv;
}

// ---- xw3 = h2n @ W2^T -> bf16 (W2 rows in registers, h2n scalar-broadcast) --
#define G3_CHUNK 40
__global__ __launch_bounds__(256) void gemm3_k(const float* __restrict__ h2n,
                                               const float* __restrict__ W2,
                                               unsigned short* __restrict__ xw3) {
    const int t = threadIdx.x;
    const int h0 = t << 1;             // columns h0, h0+1 of [0,512)
    float w0[H2], w1[H2];
#pragma unroll
    for (int k = 0; k < H2; k++) {
        w0[k] = W2[(size_t)h0 * H2 + k];
        w1[k] = W2[(size_t)h0 * H2 + H2 + k];
    }
    const int n0 = blockIdx.x * G3_CHUNK;
    const int nend = (n0 + G3_CHUNK < N_NODES) ? n0 + G3_CHUNK : N_NODES;
    for (int n = n0; n < nend; n++) {
        const float* hr = h2n + (size_t)n * H2;
        float a0 = 0.f, a1 = 0.f;
#pragma unroll
        for (int k = 0; k < H2; k++) {
            float hv = hr[k];
            a0 += hv * w0[k];
            a1 += hv * w1[k];
        }
        *(unsigned int*)(xw3 + (size_t)n * H1 + h0) = packrne(a0, a1);
    }
}

// ---- finalize: MSE = (sumF2 - 2*cross + quad) / (N*F) -----------------------
__global__ void finalize_k(const double* __restrict__ partial, float* __restrict__ out) {
    out[0] = (float)((partial[0] - 2.0 * partial[1] + partial[2]) *
                     (1.0 / ((double)N_NODES * (double)N_FEAT)));
}

extern "C" void kernel_launch(void* const* d_in, const int* in_sizes, int n_in,
                              void* d_out, int out_size, void* d_ws, size_t ws_size,
                              hipStream_t stream) {
    const float* features = (const float*)d_in[0];
    const int*   ei       = (const int*)d_in[1];
    const float* W1       = (const float*)d_in[2];
    const float* atts     = (const float*)d_in[3];
    const float* attd     = (const float*)d_in[4];
    const float* W2       = (const float*)d_in[5];
    float* out = (float*)d_out;

    char* ws = (char*)d_ws;
    unsigned short* xw1bf = (unsigned short*)(ws);              // 20,480,000 B (stays live for cross term)
    unsigned short* h3bf  = (unsigned short*)(ws + 20480000);   // 20,480,000 B
    unsigned short* h1bf  = (unsigned short*)(ws + 40960000);   // 20,480,000 B (reused for xw3 after gemm2)
    unsigned short* w1bf  = (unsigned short*)(ws + 61440000);   //  2,097,152 B
    unsigned short* w1tbf = (unsigned short*)(ws + 63537152);   //  2,097,152 B
    float* h2n      = (float*)(ws + 65634304);                  //  2,400,000 B (reused for Gbf after gemm3)
    unsigned short* Gbf = (unsigned short*)(ws + 65634304);     //  524,288 B (aliases h2n, used after gemm3)
    // zero region (single memset): a1s,a1d,den,deg,partial(double[4])
    float*  a1s     = (float*) (ws + 68034304);                 // 80,000
    float*  a1d     = (float*) (ws + 68114304);                 // 80,000
    float*  den     = (float*) (ws + 68194304);                 // 80,000
    int*    deg     = (int*)   (ws + 68274304);                 // 80,000
    double* partial = (double*)(ws + 68354304);                 // 32 (sumF2, cross, quad)
    float* ebuf     = (float*)(ws + 68354336);                  // 880,000
    int*   off      = (int*)  (ws + 69234336);
    int*   cursor   = (int*)  (ws + 69314336);
    int*   csr_src  = (int*)  (ws + 69394336);                  // 880,000
    float* csr_coef = (float*)(ws + 70274336);                  // 880,000

    hipMemsetAsync(a1s, 0, 320032, stream);  // a1s,a1d,den,deg,partial

    // 0) W1 -> bf16 (straight + transposed)
    cvtW1<<<dim3(16, 64), 256, 0, stream>>>(W1, w1bf, w1tbf);

    // 1) xw1 = features @ W1 (R3/R4-proven structure) + a1s/a1d + sum(F^2)
    gemm1_mfma<<<1280, 256, 0, stream>>>(features, w1tbf, xw1bf, atts, attd, a1s, a1d, partial);

    // 2) edge attention numerators + denominators + degree counts
    edge_att<<<(E_TOT + 255) / 256, 256, 0, stream>>>(ei, a1s, a1d, ebuf, den, deg);

    // 3) CSR build (scan writes off AND cursor; memcpy eliminated)
    scan_k<<<1, 1024, 0, stream>>>(deg, off, cursor);
    bucket_k<<<(E_TOT + 255) / 256, 256, 0, stream>>>(ei, ebuf, den, cursor, csr_src, csr_coef);

    // 4) h1 = elu(gather(xw1))
    gather_elu_bf<<<N_NODES / 4, 256, 0, stream>>>(off, csr_src, csr_coef, xw1bf, h1bf);

    // 5) h2n = normalize_rows(h1 @ W2)
    gemm2_norm_bf<<<N_NODES / 8, 256, 0, stream>>>(h1bf, W2, h2n);

    // 6) xw3 = h2n @ W2^T -> h1bf (h1 dead after gemm2; xw1bf must stay live)
    gemm3_k<<<(N_NODES + G3_CHUNK - 1) / G3_CHUNK, 256, 0, stream>>>(h2n, W2, h1bf);

    // 7) h3 = elu(gather(xw3))
    gather_elu_bf<<<N_NODES / 4, 256, 0, stream>>>(off, csr_src, csr_coef, h1bf, h3bf);

    // 8) G = W1^T W1 (bf16, symmetric) into h2n's space (dead after gemm3)
    gemmg_k<<<32, 256, 0, stream>>>(w1tbf, Gbf);

    // 9) quad = sum h3 G h3^T; cross = sum xw1 .* h3 (fused epilogue)
    gemmq_k<<<1280, 256, 0, stream>>>(h3bf, Gbf, xw1bf, partial + 1, partial + 2);

    // 10) finalize: (sumF2 - 2*cross + quad) / (N*F)
    finalize_k<<<1, 1, 0, stream>>>(partial, out);
}